// Round 14
// baseline (490.871 us; speedup 1.0000x reference)
//
#include <hip/hip_runtime.h>
#include <stdint.h>

// ---------------------------------------------------------------------------
// TTLinearAttention on MI355X. Inputs fp32, output fp32.
// Round 14: R13 + two independent low-risk changes:
//  (a) gemm128 launch_bounds (256,4)->(256,5): 5 blocks/CU (5x32KB = 160KB
//      LDS exactly); clean single-variable test (R12's try was confounded).
//  (b) kv_outer 16-row chunks: halves barrier count (64->32 per block).
// GEMM = m97 2-barrier 128^2 structure, T1 XCD swizzle + T2 LDS swizzle,
// 16x16x32 MFMA (949 TF measured at (256,4)).
// Pipeline: cvt_all -> gemm128 QKV (+phi) -> kv_outer (split 16) ->
//           reduce_S -> ctx_kernel -> gemm128 outproj -> fp32 d_out.
// ---------------------------------------------------------------------------

typedef __attribute__((ext_vector_type(8))) short short8;
typedef __attribute__((ext_vector_type(4))) float f32x4;
typedef __attribute__((ext_vector_type(4))) unsigned short us4;
typedef __attribute__((ext_vector_type(8))) unsigned short us8;

#define E_DIM 1024
#define LSEQ 4096
#define NTOK 16384
#define DH 64
#define NSPLIT 16
#define ROWS_PER_SPLIT (LSEQ / NSPLIT) // 256

__device__ __forceinline__ float b2f(unsigned short u) {
    return __builtin_bit_cast(float, (uint32_t)u << 16);
}
__device__ __forceinline__ unsigned short f2b(float f) {
    uint32_t x = __builtin_bit_cast(uint32_t, f);
    x += 0x7FFFu + ((x >> 16) & 1u); // round-to-nearest-even
    return (unsigned short)(x >> 16);
}
__device__ __forceinline__ void gload16(const void* g, void* l) {
    __builtin_amdgcn_global_load_lds(
        (const __attribute__((address_space(1))) void*)g,
        (__attribute__((address_space(3))) void*)l, 16, 0, 0);
}

// ---------------------------------------------------------------------------
// cvt_all: one dispatch converts query (blocks 0..2047) and the 4 weight
// matrices (128 blocks each). Every thread: 4 x us8 groups (8192 B/block).
// ---------------------------------------------------------------------------
__global__ __launch_bounds__(256) void cvt_all(
    const float* __restrict__ q,
    const float* __restrict__ w0, const float* __restrict__ w1,
    const float* __restrict__ w2, const float* __restrict__ w3,
    unsigned short* __restrict__ dq,
    unsigned short* __restrict__ d0, unsigned short* __restrict__ d1,
    unsigned short* __restrict__ d2, unsigned short* __restrict__ d3)
{
    const int bid = blockIdx.x;
    const float* s;
    unsigned short* d;
    int base;
    if (bid < 2048) {
        s = q; d = dq; base = bid * 1024;
    } else {
        const int k = (bid - 2048) >> 7;
        s = (k == 0) ? w0 : (k == 1) ? w1 : (k == 2) ? w2 : w3;
        d = (k == 0) ? d0 : (k == 1) ? d1 : (k == 2) ? d2 : d3;
        base = ((bid - 2048) & 127) * 1024;
    }
#pragma unroll
    for (int j = 0; j < 4; ++j) {
        const int i = base + j * 256 + threadIdx.x;
        f32x4 a = ((const f32x4*)s)[(size_t)i * 2];
        f32x4 b = ((const f32x4*)s)[(size_t)i * 2 + 1];
        us8 o = { f2b(a.x), f2b(a.y), f2b(a.z), f2b(a.w),
                  f2b(b.x), f2b(b.y), f2b(b.z), f2b(b.w) };
        ((us8*)d)[i] = o;
    }
}

// ---------------------------------------------------------------------------
// gemm128: C[m,n] = phi?( sum_k A[m,k] * W[n,k] + bias[n] )   (bias fp32)
// m97 structure: 128x128 tile, BK=64, 256 threads = 4 waves (2x2), wave tile
// 64x64. LDS 32KB single-buffer; per K-tile: stage (8 gload16) -> sync ->
// 16 swizzled ds_read_b128 + 32 MFMA -> sync. 5 blocks/CU hide the drain.
// T2 swizzle: LDS[row][chunk]=global[row][chunk^(row&7)] (16B chunks);
// stage pre-swizzles source (lane&7)^(lane>>3); read XORs chunk with lane&7.
// Grid 1D XCD-swizzled: m slowest, (n,z) fastest (R6 decode).
// ---------------------------------------------------------------------------
template <bool OUTF32, int NZ>
__global__ __launch_bounds__(256, 5) void gemm128(
    const unsigned short* __restrict__ A,
    const unsigned short* __restrict__ W0, const unsigned short* __restrict__ W1,
    const unsigned short* __restrict__ W2,
    const float* __restrict__ b0, const float* __restrict__ b1,
    const float* __restrict__ b2,
    void* __restrict__ o0, void* __restrict__ o1, void* __restrict__ o2,
    int nphi)
{
    __shared__ unsigned short As[128 * 64];
    __shared__ unsigned short Bs[128 * 64];

    // --- T1 XCD swizzle (bijective: nwg = 128*8*NZ, divisible by 8) ---
    const int bid   = blockIdx.x;
    const int chunk = (128 * 8 * NZ) / 8;
    const int swz   = (bid & 7) * chunk + (bid >> 3);
    const int mt    = swz / (8 * NZ);
    const int rem   = swz % (8 * NZ);
    const int nt    = rem & 7;
    const int z     = rem >> 3;

    const unsigned short* W = (z == 0) ? W0 : ((z == 1) ? W1 : W2);
    const float* bias       = (z == 0) ? b0 : ((z == 1) ? b1 : b2);
    void* out               = (z == 0) ? o0 : ((z == 1) ? o1 : o2);
    const bool phi = z < nphi;

    const int tid  = threadIdx.x;
    const int lane = tid & 63;
    const int w    = tid >> 6;
    const int wr   = w >> 1, wc = w & 1;
    const int m0   = mt * 128;
    const int n0   = nt * 128;

    // staging: per call a wave deposits 8 rows x 128B; row&7 == lane>>3.
    const int srow = w * 8 + (lane >> 3);                // row in 32-row chunk
    const int csw  = ((lane & 7) ^ (lane >> 3)) * 8;     // pre-swizzled k-chunk
    const int rsel = lane & 15;
    const int kq   = lane >> 4;                          // 0..3

    f32x4 acc[4][4] = {};

    for (int kt = 0; kt < 16; ++kt) {
        const int k0 = kt * 64;
#pragma unroll
        for (int c = 0; c < 4; ++c) {
            const int r = c * 32 + srow;
            gload16(&A[(size_t)(m0 + r) * E_DIM + k0 + csw], &As[(c * 32 + w * 8) * 64]);
            gload16(&W[(size_t)(n0 + r) * E_DIM + k0 + csw], &Bs[(c * 32 + w * 8) * 64]);
        }
        __syncthreads();
#pragma unroll
        for (int kk = 0; kk < 2; ++kk) {
            const int kx = ((kk * 4 + kq) ^ (lane & 7)) * 8; // swizzled read
            short8 af[4], bf[4];
#pragma unroll
            for (int mi = 0; mi < 4; ++mi)
                af[mi] = *(const short8*)&As[(wr * 64 + mi * 16 + rsel) * 64 + kx];
#pragma unroll
            for (int ni = 0; ni < 4; ++ni)
                bf[ni] = *(const short8*)&Bs[(wc * 64 + ni * 16 + rsel) * 64 + kx];
            __builtin_amdgcn_s_setprio(1);
#pragma unroll
            for (int mi = 0; mi < 4; ++mi)
#pragma unroll
                for (int ni = 0; ni < 4; ++ni)
                    acc[mi][ni] = __builtin_amdgcn_mfma_f32_16x16x32_bf16(
                        af[mi], bf[ni], acc[mi][ni], 0, 0, 0);
            __builtin_amdgcn_s_setprio(0);
        }
        __syncthreads();
    }

    // epilogue: C/D layout col=lane&15, row=(lane>>4)*4+r
#pragma unroll
    for (int mi = 0; mi < 4; ++mi) {
        const int rbase = m0 + wr * 64 + mi * 16 + ((lane >> 4) << 2);
#pragma unroll
        for (int ni = 0; ni < 4; ++ni) {
            const int col = n0 + wc * 64 + ni * 16 + (lane & 15);
            const float bv = bias[col];
#pragma unroll
            for (int r = 0; r < 4; ++r) {
                float v = acc[mi][ni][r] + bv;
                if (phi) v = (v > 0.f) ? (v + 1.f) : __expf(v); // elu(v)+1
                if (OUTF32)
                    ((float*)out)[(size_t)(rbase + r) * E_DIM + col] = v;
                else
                    ((unsigned short*)out)[(size_t)(rbase + r) * E_DIM + col] = f2b(v);
            }
        }
    }
}

// ---------------------------------------------------------------------------
// kv_outer: per (b,h,split) partial S^T[j][i] = sum_l phiK[l,i]*V[l,j], Z[i].
// 16-row chunks (R14: halves barrier count vs 8-row).
// Thread (i0=(t&15)*4, j0=(t>>4)*4) owns a 4x4 outer-product tile.
// ---------------------------------------------------------------------------
__global__ __launch_bounds__(256) void kv_outer(
    const unsigned short* __restrict__ K, const unsigned short* __restrict__ V,
    float* __restrict__ Sp, float* __restrict__ Zp)
{
    __shared__ float kb[16][64];
    __shared__ float vb[16][64];
    const int split = blockIdx.x;
    const int bh    = blockIdx.y;
    const int b = bh >> 4, h = bh & 15;
    const int t  = threadIdx.x;
    const int i0 = (t & 15) * 4;
    const int j0 = (t >> 4) * 4;
    const int sr = t >> 4;        // staging row 0..15
    const int sc = (t & 15) * 4;  // staging col 0..60

    size_t gbase = ((size_t)(b * LSEQ + split * ROWS_PER_SPLIT)) * E_DIM + h * DH;

    f32x4 acc[4] = {};
    f32x4 zacc = {};

    for (int chunk = 0; chunk < ROWS_PER_SPLIT / 16; ++chunk) {
        {
            us4 uk = *(const us4*)&K[gbase + (size_t)sr * E_DIM + sc];
            us4 uv = *(const us4*)&V[gbase + (size_t)sr * E_DIM + sc];
            f32x4 fk = { b2f(uk.x), b2f(uk.y), b2f(uk.z), b2f(uk.w) };
            f32x4 fv = { b2f(uv.x), b2f(uv.y), b2f(uv.z), b2f(uv.w) };
            *(f32x4*)&kb[sr][sc] = fk;
            *(f32x4*)&vb[sr][sc] = fv;
        }
        __syncthreads();
#pragma unroll
        for (int rr = 0; rr < 16; ++rr) {
            f32x4 kv = *(const f32x4*)&kb[rr][i0];
            f32x4 vv = *(const f32x4*)&vb[rr][j0];
            acc[0] += kv * vv.x;
            acc[1] += kv * vv.y;
            acc[2] += kv * vv.z;
            acc[3] += kv * vv.w;
            if ((t >> 4) == 0) zacc += kv;
        }
        __syncthreads();
        gbase += (size_t)16 * E_DIM;
    }

    const size_t sb = ((size_t)bh * NSPLIT + split) * (DH * DH);
#pragma unroll
    for (int jj = 0; jj < 4; ++jj)
        *(f32x4*)&Sp[sb + (size_t)(j0 + jj) * DH + i0] = acc[jj];
    if ((t >> 4) == 0)
        *(f32x4*)&Zp[((size_t)bh * NSPLIT + split) * DH + i0] = zacc;
}

// ---------------------------------------------------------------------------
// reduce_S: sum the NSPLIT partials ONCE per (b,h) into a prebuilt bf16
// B-tile [S^T (64 rows) | Z (row 64) | zeros (rows 65..79)] -> Sred[bh][5120].
// ---------------------------------------------------------------------------
__global__ __launch_bounds__(256) void reduce_S(
    const float* __restrict__ Sp, const float* __restrict__ Zp,
    unsigned short* __restrict__ Sred)
{
    const int c  = blockIdx.x;  // 0..3
    const int bh = blockIdx.y;  // 0..63
    const int t  = threadIdx.x;
    unsigned short* dst = Sred + (size_t)bh * (80 * 64);

#pragma unroll
    for (int j = 0; j < 4; ++j) {
        const int e = c * 1024 + j * 256 + t;
        float s = 0.f;
#pragma unroll
        for (int p = 0; p < NSPLIT; ++p)
            s += Sp[((size_t)bh * NSPLIT + p) * (DH * DH) + e];
        dst[e] = f2b(s);
    }
    if (c == 0) {
        if (t < 64) {
            float zv = 0.f;
#pragma unroll
            for (int p = 0; p < NSPLIT; ++p)
                zv += Zp[((size_t)bh * NSPLIT + p) * DH + t];
            dst[64 * 64 + t] = f2b(zv);
        }
        for (int e = t; e < 15 * 64; e += 256) dst[65 * 64 + e] = 0;
    }
}

// ---------------------------------------------------------------------------
// ctx_kernel: per (b,h): copy prebuilt B-tile (10KB) into LDS, then
// num+denom via MFMA (5 n-frags, K=64); ctx = num/(denom+eps).
// ---------------------------------------------------------------------------
__global__ __launch_bounds__(256) void ctx_kernel(
    const unsigned short* __restrict__ Q, const unsigned short* __restrict__ Sred,
    unsigned short* __restrict__ ctx)
{
    __shared__ unsigned short Bs[80 * 64];
    const int bh = blockIdx.y;
    const int b = bh >> 4, h = bh & 15;
    const int t    = threadIdx.x;
    const int lane = t & 63;
    const int w    = t >> 6;

    {
        const us8* src = (const us8*)(Sred + (size_t)bh * (80 * 64));
        us8* dstl = (us8*)Bs;
        for (int i = t; i < 640; i += 256) dstl[i] = src[i];
    }
    __syncthreads();

    const int m0 = blockIdx.x * 256 + w * 64;
    f32x4 acc[4][5] = {};
#pragma unroll
    for (int kk = 0; kk < 2; ++kk) {
        const int krd = kk * 32 + (lane >> 4) * 8;
        short8 af[4];
#pragma unroll
        for (int mi = 0; mi < 4; ++mi) {
            const int l = m0 + mi * 16 + (lane & 15);
            af[mi] = *(const short8*)&Q[((size_t)(b * LSEQ + l)) * E_DIM + h * DH + krd];
        }
#pragma unroll
        for (int ni = 0; ni < 5; ++ni) {
            short8 bfr = *(const short8*)&Bs[(ni * 16 + (lane & 15)) * 64 + krd];
#pragma unroll
            for (int mi = 0; mi < 4; ++mi)
                acc[mi][ni] = __builtin_amdgcn_mfma_f32_16x16x32_bf16(
                    af[mi], bfr, acc[mi][ni], 0, 0, 0);
        }
    }
#pragma unroll
    for (int mi = 0; mi < 4; ++mi) {
#pragma unroll
        for (int r = 0; r < 4; ++r) {
            const float dv  = __shfl(acc[mi][4][r], lane & 48, 64); // denom (col 64)
            const float inv = 1.f / (dv + 1e-6f);
            const int l = m0 + mi * 16 + ((lane >> 4) << 2) + r;
#pragma unroll
            for (int ni = 0; ni < 4; ++ni)
                ctx[((size_t)(b * LSEQ + l)) * E_DIM + h * DH + ni * 16 + (lane & 15)] =
                    f2b(acc[mi][ni][r] * inv);
        }
    }
}

// ---------------------------------------------------------------------------
extern "C" void kernel_launch(void* const* d_in, const int* in_sizes, int n_in,
                              void* d_out, int out_size, void* d_ws, size_t ws_size,
                              hipStream_t stream)
{
    const float* query = (const float*)d_in[0];
    const float* Wq = (const float*)d_in[1];
    const float* bq = (const float*)d_in[2];
    const float* Wk = (const float*)d_in[3];
    const float* bk = (const float*)d_in[4];
    const float* Wv = (const float*)d_in[5];
    const float* bv = (const float*)d_in[6];
    const float* Wo = (const float*)d_in[7];
    const float* bo = (const float*)d_in[8];

    // ws (136 MiB peak):
    //   [qb 32MiB | Wob 2 | Wqb 2 | Wkb 2 | Wvb 2 | phiQ 32 | phiK 32 | Vw 32]
    //   Sp/Zp (16.25 MiB) alias qb after gemm1; Sred (640KB) aliases Wqb;
    //   ctx aliases phiK.
    unsigned short* qb   = (unsigned short*)d_ws;
    unsigned short* Wob  = qb  + (size_t)NTOK * E_DIM;
    unsigned short* Wqb  = Wob + (size_t)E_DIM * E_DIM;
    unsigned short* Wkb  = Wqb + (size_t)E_DIM * E_DIM;
    unsigned short* Wvb  = Wkb + (size_t)E_DIM * E_DIM;
    unsigned short* phiQ = Wvb + (size_t)E_DIM * E_DIM;
    unsigned short* phiK = phiQ + (size_t)NTOK * E_DIM;
    unsigned short* Vw   = phiK + (size_t)NTOK * E_DIM;
    float* Sp = (float*)qb;                           // [64][NSPLIT][64*64] f32
    float* Zp = Sp + (size_t)64 * NSPLIT * DH * DH;   // [64][NSPLIT][64] f32
    unsigned short* Sred = Wqb;                       // [64][80*64] bf16
    unsigned short* ctx = phiK;                       // phiK dead after kv_outer

    // 0) fp32 -> bf16 (query + 4 weights, one dispatch)
    cvt_all<<<dim3(2048 + 4 * 128), 256, 0, stream>>>(query, Wq, Wk, Wv, Wo,
                                                      qb, Wqb, Wkb, Wvb, Wob);
    // 1) QKV projections (+phi on Q,K) -> bf16; 128 m-tiles x 8 n-tiles x 3
    gemm128<false, 3><<<dim3(3072), 256, 0, stream>>>(qb, Wqb, Wkb, Wvb,
                                                      bq, bk, bv,
                                                      phiQ, phiK, Vw, 2);
    // 2) S^T/Z partials (Sp/Zp overwrite dead qb)
    kv_outer<<<dim3(NSPLIT, 64), 256, 0, stream>>>(phiK, Vw, Sp, Zp);
    // 2b) sum partials once -> prebuilt bf16 B-tile per bh (overwrites Wqb)
    reduce_S<<<dim3(4, 64), 256, 0, stream>>>(Sp, Zp, Sred);
    // 3) context -> bf16
    ctx_kernel<<<dim3(LSEQ / 256, 64), 256, 0, stream>>>(phiQ, Sred, ctx);
    // 4) output projection -> FP32 d_out; 128 x 8 tiles
    gemm128<true, 1><<<dim3(1024), 256, 0, stream>>>(ctx, Wob, Wob, Wob,
                                                     bo, bo, bo,
                                                     d_out, d_out, d_out, 0);
}

// Round 15
// 226.353 us; speedup vs baseline: 2.1686x; 2.1686x over previous
//
#include <hip/hip_runtime.h>
#include <stdint.h>

// ---------------------------------------------------------------------------
// TTLinearAttention on MI355X. Inputs fp32, output fp32.
// Round 15: revert R14's launch_bounds(256,5) -> (256,4). At 5 waves/SIMD the
// VGPR budget fell below the kernel's 64-VGPR working set -> accumulator
// spills (VGPR 48, WRITE_SIZE 581MB, MfmaUtil 13%). (256,4) + 64 VGPR is the
// proven optimum (949 TF QKV). kv_outer keeps R14's 16-row chunks.
// GEMM = m97 2-barrier 128^2 structure, T1 XCD swizzle + T2 LDS swizzle.
// Pipeline: cvt_all -> gemm128 QKV (+phi) -> kv_outer (split 16) ->
//           reduce_S -> ctx_kernel -> gemm128 outproj -> fp32 d_out.
// ---------------------------------------------------------------------------

typedef __attribute__((ext_vector_type(8))) short short8;
typedef __attribute__((ext_vector_type(4))) float f32x4;
typedef __attribute__((ext_vector_type(4))) unsigned short us4;
typedef __attribute__((ext_vector_type(8))) unsigned short us8;

#define E_DIM 1024
#define LSEQ 4096
#define NTOK 16384
#define DH 64
#define NSPLIT 16
#define ROWS_PER_SPLIT (LSEQ / NSPLIT) // 256

__device__ __forceinline__ float b2f(unsigned short u) {
    return __builtin_bit_cast(float, (uint32_t)u << 16);
}
__device__ __forceinline__ unsigned short f2b(float f) {
    uint32_t x = __builtin_bit_cast(uint32_t, f);
    x += 0x7FFFu + ((x >> 16) & 1u); // round-to-nearest-even
    return (unsigned short)(x >> 16);
}
__device__ __forceinline__ void gload16(const void* g, void* l) {
    __builtin_amdgcn_global_load_lds(
        (const __attribute__((address_space(1))) void*)g,
        (__attribute__((address_space(3))) void*)l, 16, 0, 0);
}

// ---------------------------------------------------------------------------
// cvt_all: one dispatch converts query (blocks 0..2047) and the 4 weight
// matrices (128 blocks each). Every thread: 4 x us8 groups (8192 B/block).
// ---------------------------------------------------------------------------
__global__ __launch_bounds__(256) void cvt_all(
    const float* __restrict__ q,
    const float* __restrict__ w0, const float* __restrict__ w1,
    const float* __restrict__ w2, const float* __restrict__ w3,
    unsigned short* __restrict__ dq,
    unsigned short* __restrict__ d0, unsigned short* __restrict__ d1,
    unsigned short* __restrict__ d2, unsigned short* __restrict__ d3)
{
    const int bid = blockIdx.x;
    const float* s;
    unsigned short* d;
    int base;
    if (bid < 2048) {
        s = q; d = dq; base = bid * 1024;
    } else {
        const int k = (bid - 2048) >> 7;
        s = (k == 0) ? w0 : (k == 1) ? w1 : (k == 2) ? w2 : w3;
        d = (k == 0) ? d0 : (k == 1) ? d1 : (k == 2) ? d2 : d3;
        base = ((bid - 2048) & 127) * 1024;
    }
#pragma unroll
    for (int j = 0; j < 4; ++j) {
        const int i = base + j * 256 + threadIdx.x;
        f32x4 a = ((const f32x4*)s)[(size_t)i * 2];
        f32x4 b = ((const f32x4*)s)[(size_t)i * 2 + 1];
        us8 o = { f2b(a.x), f2b(a.y), f2b(a.z), f2b(a.w),
                  f2b(b.x), f2b(b.y), f2b(b.z), f2b(b.w) };
        ((us8*)d)[i] = o;
    }
}

// ---------------------------------------------------------------------------
// gemm128: C[m,n] = phi?( sum_k A[m,k] * W[n,k] + bias[n] )   (bias fp32)
// m97 structure: 128x128 tile, BK=64, 256 threads = 4 waves (2x2), wave tile
// 64x64. LDS 32KB single-buffer; per K-tile: stage (8 gload16) -> sync ->
// 16 swizzled ds_read_b128 + 32 MFMA -> sync. launch_bounds(256,4), 64 VGPR.
// T2 swizzle: LDS[row][chunk]=global[row][chunk^(row&7)] (16B chunks);
// stage pre-swizzles source (lane&7)^(lane>>3); read XORs chunk with lane&7.
// Grid 1D XCD-swizzled: m slowest, (n,z) fastest (R6 decode).
// ---------------------------------------------------------------------------
template <bool OUTF32, int NZ>
__global__ __launch_bounds__(256, 4) void gemm128(
    const unsigned short* __restrict__ A,
    const unsigned short* __restrict__ W0, const unsigned short* __restrict__ W1,
    const unsigned short* __restrict__ W2,
    const float* __restrict__ b0, const float* __restrict__ b1,
    const float* __restrict__ b2,
    void* __restrict__ o0, void* __restrict__ o1, void* __restrict__ o2,
    int nphi)
{
    __shared__ unsigned short As[128 * 64];
    __shared__ unsigned short Bs[128 * 64];

    // --- T1 XCD swizzle (bijective: nwg = 128*8*NZ, divisible by 8) ---
    const int bid   = blockIdx.x;
    const int chunk = (128 * 8 * NZ) / 8;
    const int swz   = (bid & 7) * chunk + (bid >> 3);
    const int mt    = swz / (8 * NZ);
    const int rem   = swz % (8 * NZ);
    const int nt    = rem & 7;
    const int z     = rem >> 3;

    const unsigned short* W = (z == 0) ? W0 : ((z == 1) ? W1 : W2);
    const float* bias       = (z == 0) ? b0 : ((z == 1) ? b1 : b2);
    void* out               = (z == 0) ? o0 : ((z == 1) ? o1 : o2);
    const bool phi = z < nphi;

    const int tid  = threadIdx.x;
    const int lane = tid & 63;
    const int w    = tid >> 6;
    const int wr   = w >> 1, wc = w & 1;
    const int m0   = mt * 128;
    const int n0   = nt * 128;

    // staging: per call a wave deposits 8 rows x 128B; row&7 == lane>>3.
    const int srow = w * 8 + (lane >> 3);                // row in 32-row chunk
    const int csw  = ((lane & 7) ^ (lane >> 3)) * 8;     // pre-swizzled k-chunk
    const int rsel = lane & 15;
    const int kq   = lane >> 4;                          // 0..3

    f32x4 acc[4][4] = {};

    for (int kt = 0; kt < 16; ++kt) {
        const int k0 = kt * 64;
#pragma unroll
        for (int c = 0; c < 4; ++c) {
            const int r = c * 32 + srow;
            gload16(&A[(size_t)(m0 + r) * E_DIM + k0 + csw], &As[(c * 32 + w * 8) * 64]);
            gload16(&W[(size_t)(n0 + r) * E_DIM + k0 + csw], &Bs[(c * 32 + w * 8) * 64]);
        }
        __syncthreads();
#pragma unroll
        for (int kk = 0; kk < 2; ++kk) {
            const int kx = ((kk * 4 + kq) ^ (lane & 7)) * 8; // swizzled read
            short8 af[4], bf[4];
#pragma unroll
            for (int mi = 0; mi < 4; ++mi)
                af[mi] = *(const short8*)&As[(wr * 64 + mi * 16 + rsel) * 64 + kx];
#pragma unroll
            for (int ni = 0; ni < 4; ++ni)
                bf[ni] = *(const short8*)&Bs[(wc * 64 + ni * 16 + rsel) * 64 + kx];
            __builtin_amdgcn_s_setprio(1);
#pragma unroll
            for (int mi = 0; mi < 4; ++mi)
#pragma unroll
                for (int ni = 0; ni < 4; ++ni)
                    acc[mi][ni] = __builtin_amdgcn_mfma_f32_16x16x32_bf16(
                        af[mi], bf[ni], acc[mi][ni], 0, 0, 0);
            __builtin_amdgcn_s_setprio(0);
        }
        __syncthreads();
    }

    // epilogue: C/D layout col=lane&15, row=(lane>>4)*4+r
#pragma unroll
    for (int mi = 0; mi < 4; ++mi) {
        const int rbase = m0 + wr * 64 + mi * 16 + ((lane >> 4) << 2);
#pragma unroll
        for (int ni = 0; ni < 4; ++ni) {
            const int col = n0 + wc * 64 + ni * 16 + (lane & 15);
            const float bv = bias[col];
#pragma unroll
            for (int r = 0; r < 4; ++r) {
                float v = acc[mi][ni][r] + bv;
                if (phi) v = (v > 0.f) ? (v + 1.f) : __expf(v); // elu(v)+1
                if (OUTF32)
                    ((float*)out)[(size_t)(rbase + r) * E_DIM + col] = v;
                else
                    ((unsigned short*)out)[(size_t)(rbase + r) * E_DIM + col] = f2b(v);
            }
        }
    }
}

// ---------------------------------------------------------------------------
// kv_outer: per (b,h,split) partial S^T[j][i] = sum_l phiK[l,i]*V[l,j], Z[i].
// 16-row chunks. Thread (i0=(t&15)*4, j0=(t>>4)*4) owns a 4x4 outer tile.
// ---------------------------------------------------------------------------
__global__ __launch_bounds__(256) void kv_outer(
    const unsigned short* __restrict__ K, const unsigned short* __restrict__ V,
    float* __restrict__ Sp, float* __restrict__ Zp)
{
    __shared__ float kb[16][64];
    __shared__ float vb[16][64];
    const int split = blockIdx.x;
    const int bh    = blockIdx.y;
    const int b = bh >> 4, h = bh & 15;
    const int t  = threadIdx.x;
    const int i0 = (t & 15) * 4;
    const int j0 = (t >> 4) * 4;
    const int sr = t >> 4;        // staging row 0..15
    const int sc = (t & 15) * 4;  // staging col 0..60

    size_t gbase = ((size_t)(b * LSEQ + split * ROWS_PER_SPLIT)) * E_DIM + h * DH;

    f32x4 acc[4] = {};
    f32x4 zacc = {};

    for (int chunk = 0; chunk < ROWS_PER_SPLIT / 16; ++chunk) {
        {
            us4 uk = *(const us4*)&K[gbase + (size_t)sr * E_DIM + sc];
            us4 uv = *(const us4*)&V[gbase + (size_t)sr * E_DIM + sc];
            f32x4 fk = { b2f(uk.x), b2f(uk.y), b2f(uk.z), b2f(uk.w) };
            f32x4 fv = { b2f(uv.x), b2f(uv.y), b2f(uv.z), b2f(uv.w) };
            *(f32x4*)&kb[sr][sc] = fk;
            *(f32x4*)&vb[sr][sc] = fv;
        }
        __syncthreads();
#pragma unroll
        for (int rr = 0; rr < 16; ++rr) {
            f32x4 kv = *(const f32x4*)&kb[rr][i0];
            f32x4 vv = *(const f32x4*)&vb[rr][j0];
            acc[0] += kv * vv.x;
            acc[1] += kv * vv.y;
            acc[2] += kv * vv.z;
            acc[3] += kv * vv.w;
            if ((t >> 4) == 0) zacc += kv;
        }
        __syncthreads();
        gbase += (size_t)16 * E_DIM;
    }

    const size_t sb = ((size_t)bh * NSPLIT + split) * (DH * DH);
#pragma unroll
    for (int jj = 0; jj < 4; ++jj)
        *(f32x4*)&Sp[sb + (size_t)(j0 + jj) * DH + i0] = acc[jj];
    if ((t >> 4) == 0)
        *(f32x4*)&Zp[((size_t)bh * NSPLIT + split) * DH + i0] = zacc;
}

// ---------------------------------------------------------------------------
// reduce_S: sum the NSPLIT partials ONCE per (b,h) into a prebuilt bf16
// B-tile [S^T (64 rows) | Z (row 64) | zeros (rows 65..79)] -> Sred[bh][5120].
// ---------------------------------------------------------------------------
__global__ __launch_bounds__(256) void reduce_S(
    const float* __restrict__ Sp, const float* __restrict__ Zp,
    unsigned short* __restrict__ Sred)
{
    const int c  = blockIdx.x;  // 0..3
    const int bh = blockIdx.y;  // 0..63
    const int t  = threadIdx.x;
    unsigned short* dst = Sred + (size_t)bh * (80 * 64);

#pragma unroll
    for (int j = 0; j < 4; ++j) {
        const int e = c * 1024 + j * 256 + t;
        float s = 0.f;
#pragma unroll
        for (int p = 0; p < NSPLIT; ++p)
            s += Sp[((size_t)bh * NSPLIT + p) * (DH * DH) + e];
        dst[e] = f2b(s);
    }
    if (c == 0) {
        if (t < 64) {
            float zv = 0.f;
#pragma unroll
            for (int p = 0; p < NSPLIT; ++p)
                zv += Zp[((size_t)bh * NSPLIT + p) * DH + t];
            dst[64 * 64 + t] = f2b(zv);
        }
        for (int e = t; e < 15 * 64; e += 256) dst[65 * 64 + e] = 0;
    }
}

// ---------------------------------------------------------------------------
// ctx_kernel: per (b,h): copy prebuilt B-tile (10KB) into LDS, then
// num+denom via MFMA (5 n-frags, K=64); ctx = num/(denom+eps).
// ---------------------------------------------------------------------------
__global__ __launch_bounds__(256) void ctx_kernel(
    const unsigned short* __restrict__ Q, const unsigned short* __restrict__ Sred,
    unsigned short* __restrict__ ctx)
{
    __shared__ unsigned short Bs[80 * 64];
    const int bh = blockIdx.y;
    const int b = bh >> 4, h = bh & 15;
    const int t    = threadIdx.x;
    const int lane = t & 63;
    const int w    = t >> 6;

    {
        const us8* src = (const us8*)(Sred + (size_t)bh * (80 * 64));
        us8* dstl = (us8*)Bs;
        for (int i = t; i < 640; i += 256) dstl[i] = src[i];
    }
    __syncthreads();

    const int m0 = blockIdx.x * 256 + w * 64;
    f32x4 acc[4][5] = {};
#pragma unroll
    for (int kk = 0; kk < 2; ++kk) {
        const int krd = kk * 32 + (lane >> 4) * 8;
        short8 af[4];
#pragma unroll
        for (int mi = 0; mi < 4; ++mi) {
            const int l = m0 + mi * 16 + (lane & 15);
            af[mi] = *(const short8*)&Q[((size_t)(b * LSEQ + l)) * E_DIM + h * DH + krd];
        }
#pragma unroll
        for (int ni = 0; ni < 5; ++ni) {
            short8 bfr = *(const short8*)&Bs[(ni * 16 + (lane & 15)) * 64 + krd];
#pragma unroll
            for (int mi = 0; mi < 4; ++mi)
                acc[mi][ni] = __builtin_amdgcn_mfma_f32_16x16x32_bf16(
                    af[mi], bfr, acc[mi][ni], 0, 0, 0);
        }
    }
#pragma unroll
    for (int mi = 0; mi < 4; ++mi) {
#pragma unroll
        for (int r = 0; r < 4; ++r) {
            const float dv  = __shfl(acc[mi][4][r], lane & 48, 64); // denom (col 64)
            const float inv = 1.f / (dv + 1e-6f);
            const int l = m0 + mi * 16 + ((lane >> 4) << 2) + r;
#pragma unroll
            for (int ni = 0; ni < 4; ++ni)
                ctx[((size_t)(b * LSEQ + l)) * E_DIM + h * DH + ni * 16 + (lane & 15)] =
                    f2b(acc[mi][ni][r] * inv);
        }
    }
}

// ---------------------------------------------------------------------------
extern "C" void kernel_launch(void* const* d_in, const int* in_sizes, int n_in,
                              void* d_out, int out_size, void* d_ws, size_t ws_size,
                              hipStream_t stream)
{
    const float* query = (const float*)d_in[0];
    const float* Wq = (const float*)d_in[1];
    const float* bq = (const float*)d_in[2];
    const float* Wk = (const float*)d_in[3];
    const float* bk = (const float*)d_in[4];
    const float* Wv = (const float*)d_in[5];
    const float* bv = (const float*)d_in[6];
    const float* Wo = (const float*)d_in[7];
    const float* bo = (const float*)d_in[8];

    // ws (136 MiB peak):
    //   [qb 32MiB | Wob 2 | Wqb 2 | Wkb 2 | Wvb 2 | phiQ 32 | phiK 32 | Vw 32]
    //   Sp/Zp (16.25 MiB) alias qb after gemm1; Sred (640KB) aliases Wqb;
    //   ctx aliases phiK.
    unsigned short* qb   = (unsigned short*)d_ws;
    unsigned short* Wob  = qb  + (size_t)NTOK * E_DIM;
    unsigned short* Wqb  = Wob + (size_t)E_DIM * E_DIM;
    unsigned short* Wkb  = Wqb + (size_t)E_DIM * E_DIM;
    unsigned short* Wvb  = Wkb + (size_t)E_DIM * E_DIM;
    unsigned short* phiQ = Wvb + (size_t)E_DIM * E_DIM;
    unsigned short* phiK = phiQ + (size_t)NTOK * E_DIM;
    unsigned short* Vw   = phiK + (size_t)NTOK * E_DIM;
    float* Sp = (float*)qb;                           // [64][NSPLIT][64*64] f32
    float* Zp = Sp + (size_t)64 * NSPLIT * DH * DH;   // [64][NSPLIT][64] f32
    unsigned short* Sred = Wqb;                       // [64][80*64] bf16
    unsigned short* ctx = phiK;                       // phiK dead after kv_outer

    // 0) fp32 -> bf16 (query + 4 weights, one dispatch)
    cvt_all<<<dim3(2048 + 4 * 128), 256, 0, stream>>>(query, Wq, Wk, Wv, Wo,
                                                      qb, Wqb, Wkb, Wvb, Wob);
    // 1) QKV projections (+phi on Q,K) -> bf16; 128 m-tiles x 8 n-tiles x 3
    gemm128<false, 3><<<dim3(3072), 256, 0, stream>>>(qb, Wqb, Wkb, Wvb,
                                                      bq, bk, bv,
                                                      phiQ, phiK, Vw, 2);
    // 2) S^T/Z partials (Sp/Zp overwrite dead qb)
    kv_outer<<<dim3(NSPLIT, 64), 256, 0, stream>>>(phiK, Vw, Sp, Zp);
    // 2b) sum partials once -> prebuilt bf16 B-tile per bh (overwrites Wqb)
    reduce_S<<<dim3(4, 64), 256, 0, stream>>>(Sp, Zp, Sred);
    // 3) context -> bf16
    ctx_kernel<<<dim3(LSEQ / 256, 64), 256, 0, stream>>>(phiQ, Sred, ctx);
    // 4) output projection -> FP32 d_out; 128 x 8 tiles
    gemm128<true, 1><<<dim3(1024), 256, 0, stream>>>(ctx, Wob, Wob, Wob,
                                                     bo, bo, bo,
                                                     d_out, d_out, d_out, 0);
}